// Round 3
// baseline (249.636 us; speedup 1.0000x reference)
//
#include <hip/hip_runtime.h>
#include <hip/hip_bf16.h>
#include <stdint.h>

// B=4, T=2048, INPUT_DIM=1024, DIM=64, H=16
typedef __attribute__((ext_vector_type(8))) short bf16x8;
typedef __attribute__((ext_vector_type(4))) short s16x4;
typedef __attribute__((ext_vector_type(4))) float f32x4;

__device__ __forceinline__ void mfma_bf16(f32x4& c, bf16x8 a, bf16x8 b) {
  asm("v_mfma_f32_16x16x32_bf16 %0, %1, %2, %0" : "+v"(c) : "v"(a), "v"(b));
}

__device__ __forceinline__ void gload_lds16(const void* g, void* lds) {
  __builtin_amdgcn_global_load_lds(
      (const __attribute__((address_space(1))) void*)g,
      (__attribute__((address_space(3))) void*)lds, 16, 0, 0);
}

// ---------------- f32 -> bf16 convert (vectorized) ----------------
__global__ void cvt_f32_bf16(const float* __restrict__ in, __hip_bfloat16* __restrict__ out, int n4) {
  int i = blockIdx.x * blockDim.x + threadIdx.x;
  if (i >= n4) return;
  float4 v = reinterpret_cast<const float4*>(in)[i];
  __hip_bfloat162 a = __float22bfloat162_rn(make_float2(v.x, v.y));
  __hip_bfloat162 b = __float22bfloat162_rn(make_float2(v.z, v.w));
  reinterpret_cast<__hip_bfloat162*>(out)[i * 2]     = a;
  reinterpret_cast<__hip_bfloat162*>(out)[i * 2 + 1] = b;
}

// ------------- transpose [R][C] f32 -> [C][R] bf16 -------------
__global__ void transpose_cvt(const float* __restrict__ in, __hip_bfloat16* __restrict__ out,
                              int R, int C) {
  __shared__ float tile[32][33];
  int c0 = blockIdx.x * 32, r0 = blockIdx.y * 32;
#pragma unroll
  for (int k = 0; k < 4; k++)
    tile[threadIdx.y + 8 * k][threadIdx.x] =
        in[(size_t)(r0 + threadIdx.y + 8 * k) * C + c0 + threadIdx.x];
  __syncthreads();
#pragma unroll
  for (int k = 0; k < 4; k++)
    out[(size_t)(c0 + threadIdx.y + 8 * k) * R + r0 + threadIdx.x] =
        __float2bfloat16(tile[threadIdx.x][threadIdx.y + 8 * k]);
}

// ---------------- bf16 GEMM, m97 structure: 128x128 tile, BK=32 ----------------
// A: [M][K] row-major bf16 ; Bt: [N][K] row-major bf16
// MODE 0: scatter Q (scaled 0.125*log2e) / K into [B,H,T,64]   (n-cols 0..2047)
// MODE 1: f32 out + bias
// MODE 2: V-tiles (n-cols 2048..3071): swapped mfma -> C^T, scatter Vt [bh][d][t]
template <int MODE>
__global__ __launch_bounds__(256) void gemm_bf16(
    const __hip_bfloat16* __restrict__ A, const __hip_bfloat16* __restrict__ Bt,
    int M, int N, int K,
    __hip_bfloat16* __restrict__ qb, __hip_bfloat16* __restrict__ kb,
    __hip_bfloat16* __restrict__ vt,
    float* __restrict__ outp, const float* __restrict__ bias) {
  constexpr int BK = 32;
  __shared__ __align__(16) __hip_bfloat16 As[128 * BK];
  __shared__ __align__(16) __hip_bfloat16 Bs[128 * BK];
  const int tid = threadIdx.x;
  const int wave = tid >> 6, lane = tid & 63;
  const int wr = wave >> 1, wc = wave & 1;
  const int m0 = blockIdx.y * 128;
  const int n0 = (MODE == 2 ? 2048 : 0) + blockIdx.x * 128;

  f32x4 acc[4][4];
#pragma unroll
  for (int i = 0; i < 4; i++)
#pragma unroll
    for (int j = 0; j < 4; j++) acc[i][j] = (f32x4)(0.0f);

  const int c0 = wave * 2, c1 = c0 + 1;
  const int srow0 = c0 * 16 + (lane >> 2);
  const int srow1 = c1 * 16 + (lane >> 2);
  const int scol = (lane & 3) * 8;
  const __hip_bfloat16* Ag0 = A + (size_t)(m0 + srow0) * K + scol;
  const __hip_bfloat16* Ag1 = A + (size_t)(m0 + srow1) * K + scol;
  const __hip_bfloat16* Bg0 = Bt + (size_t)(n0 + srow0) * K + scol;
  const __hip_bfloat16* Bg1 = Bt + (size_t)(n0 + srow1) * K + scol;
  __hip_bfloat16* AsP0 = &As[c0 * 512];
  __hip_bfloat16* AsP1 = &As[c1 * 512];
  __hip_bfloat16* BsP0 = &Bs[c0 * 512];
  __hip_bfloat16* BsP1 = &Bs[c1 * 512];

  for (int kk = 0; kk < K; kk += BK) {
    gload_lds16(Ag0 + kk, AsP0);
    gload_lds16(Ag1 + kk, AsP1);
    gload_lds16(Bg0 + kk, BsP0);
    gload_lds16(Bg1 + kk, BsP1);
    __syncthreads();
    bf16x8 af[4], bfr[4];
#pragma unroll
    for (int i = 0; i < 4; i++)
      af[i] = *(const bf16x8*)&As[(wr * 64 + i * 16 + (lane & 15)) * BK + (lane >> 4) * 8];
#pragma unroll
    for (int j = 0; j < 4; j++)
      bfr[j] = *(const bf16x8*)&Bs[(wc * 64 + j * 16 + (lane & 15)) * BK + (lane >> 4) * 8];
#pragma unroll
    for (int i = 0; i < 4; i++)
#pragma unroll
      for (int j = 0; j < 4; j++) {
        if constexpr (MODE == 2)
          mfma_bf16(acc[i][j], bfr[j], af[i]);  // D = C^T fragment
        else
          mfma_bf16(acc[i][j], af[i], bfr[j]);
      }
    __syncthreads();
  }

  if constexpr (MODE == 0) {
#pragma unroll
    for (int j = 0; j < 4; j++) {
      int col = n0 + wc * 64 + j * 16 + (lane & 15);  // col = sel*1024 + h*64 + d
      int sel = col >> 10;                            // 0=Q, 1=K
      int h = (col >> 6) & 15;
      int d = col & 63;
      __hip_bfloat16* dst = sel ? kb : qb;
      // Q: fold 1/sqrt(64) AND log2(e) so softmax runs in base-2 domain
      float scl = sel ? 1.0f : 0.18033688f;
#pragma unroll
      for (int i = 0; i < 4; i++) {
#pragma unroll
        for (int r = 0; r < 4; r++) {
          int row = m0 + wr * 64 + i * 16 + (lane >> 4) * 4 + r;  // b*2048 + t
          int b = row >> 11, t = row & 2047;
          dst[(((size_t)b * 16 + h) * 2048 + t) * 64 + d] = __float2bfloat16(acc[i][j][r] * scl);
        }
      }
    }
  } else if constexpr (MODE == 2) {
    // acc[i][j]: col(lane&15) = m-index (t), row(reg) = n-index (head/d)
#pragma unroll
    for (int j = 0; j < 4; j++) {
#pragma unroll
      for (int r = 0; r < 4; r++) {
        int nrow = n0 + wc * 64 + j * 16 + (lane >> 4) * 4 + r;  // 2048 + h*64 + d
        int h = (nrow >> 6) & 15;
        int d = nrow & 63;
#pragma unroll
        for (int i = 0; i < 4; i++) {
          int tcol = m0 + wr * 64 + i * 16 + (lane & 15);  // b*2048 + t
          int b = tcol >> 11, t = tcol & 2047;
          vt[(((size_t)b * 16 + h) * 64 + d) * 2048 + t] = __float2bfloat16(acc[i][j][r]);
        }
      }
    }
  } else {
#pragma unroll
    for (int j = 0; j < 4; j++) {
      int col = n0 + wc * 64 + j * 16 + (lane & 15);
      float bv = bias[col];
#pragma unroll
      for (int i = 0; i < 4; i++) {
#pragma unroll
        for (int r = 0; r < 4; r++) {
          int row = m0 + wr * 64 + i * 16 + (lane >> 4) * 4 + r;
          outp[(size_t)row * N + col] = acc[i][j][r] + bv;
        }
      }
    }
  }
}

// ---------------- flash attention ----------------
// Q,K: [bh][t][64] bf16 (Q pre-scaled by 0.125*log2e -> base-2 softmax).
// Vt: [bh][d][2048] bf16. Out: [b*T + t][1024] bf16.
// 4 waves, 64 q-rows/block (16/wave), KV tiles of 64, double-buffered LDS,
// counted vmcnt(4) prefetch. Swapped QK^T: lane owns q-row (lane&15).
// Softmax: base-2 online, defer-max (THR=11.5 ~ 8 nats), lazy l-reduce.
__global__ __launch_bounds__(256) void attn_fwd(
    const __hip_bfloat16* __restrict__ Qb, const __hip_bfloat16* __restrict__ Kb,
    const __hip_bfloat16* __restrict__ Vtg, __hip_bfloat16* __restrict__ Ob) {
  constexpr int T = 2048;
  constexpr float THR = 11.5f;  // log2 domain
  __shared__ __align__(16) __hip_bfloat16 Ks[2][4096];     // [key][d] image, swizzled
  __shared__ __align__(16) __hip_bfloat16 Vs[2][4096];     // [d][key] image, swizzled
  __shared__ __align__(16) __hip_bfloat16 Ps[4][1024];     // per-wave P[qrow][key], swizzled
  const int tid = threadIdx.x, wave = tid >> 6, lane = tid & 63;

  // XCD-aware swizzle: 2048 blocks, XCD x gets bh 8x..8x+7 (K/V L2 locality)
  int id = ((int)blockIdx.x & 7) * 256 + ((int)blockIdx.x >> 3);
  const int bh = id >> 5, q0 = (id & 31) * 64;
  const size_t baseQ = (size_t)bh * T * 64;
  const size_t baseV = (size_t)bh * 64 * T;

  bf16x8 qf[2];
  {
    const int qrow = q0 + wave * 16 + (lane & 15);
#pragma unroll
    for (int ks = 0; ks < 2; ks++)
      qf[ks] = *(const bf16x8*)&Qb[baseQ + (size_t)qrow * 64 + ks * 32 + (lane >> 4) * 8];
  }

  float m_run = -3.0e38f;
  float l_part = 0.0f;  // lane-local partial (its own 16 keys/tile); reduced at epilogue
  f32x4 o[4];
#pragma unroll
  for (int fd = 0; fd < 4; fd++) o[fd] = (f32x4)(0.0f);

  const int sr = lane >> 3;            // 0..7
  const int q8 = (lane & 7) ^ sr;      // swizzled 16B-chunk index within row
  const char* KgB = (const char*)(Kb + baseQ);
  const char* VgB = (const char*)(Vtg + baseV);
  const int cc0 = wave * 2, cc1 = cc0 + 1;
  char* PwB = (char*)&Ps[wave][0];
  const int prow = lane & 15, hi = lane >> 4;

#define STAGE(kt, buf)                                                                   \
  do {                                                                                   \
    char* kd = (char*)Ks[buf];                                                           \
    char* vd = (char*)Vs[buf];                                                           \
    gload_lds16(KgB + (size_t)((kt) * 64 + cc0 * 8 + sr) * 128 + q8 * 16, kd + cc0 * 1024); \
    gload_lds16(KgB + (size_t)((kt) * 64 + cc1 * 8 + sr) * 128 + q8 * 16, kd + cc1 * 1024); \
    gload_lds16(VgB + (size_t)(cc0 * 8 + sr) * 4096 + (kt) * 128 + q8 * 16, vd + cc0 * 1024); \
    gload_lds16(VgB + (size_t)(cc1 * 8 + sr) * 4096 + (kt) * 128 + q8 * 16, vd + cc1 * 1024); \
  } while (0)

  STAGE(0, 0);
  int cur = 0;

  for (int kt = 0; kt < T / 64; kt++) {
    if (kt < T / 64 - 1) {
      STAGE(kt + 1, cur ^ 1);
      asm volatile("s_waitcnt vmcnt(4)" ::: "memory");  // cur tile landed; 4 prefetch in flight
    } else {
      asm volatile("s_waitcnt vmcnt(0)" ::: "memory");
    }
    __builtin_amdgcn_s_barrier();
    __builtin_amdgcn_sched_barrier(0);
    const char* KsB = (const char*)Ks[cur];
    const char* VtB = (const char*)Vs[cur];

    // S^T = K · Q^T : lane owns (key = kf*16 + hi*4 + r, qrow = lane&15)
    f32x4 s[4];
#pragma unroll
    for (int kf = 0; kf < 4; kf++) s[kf] = (f32x4)(0.0f);
    __builtin_amdgcn_s_setprio(1);
#pragma unroll
    for (int ks = 0; ks < 2; ks++) {
#pragma unroll
      for (int kf = 0; kf < 4; kf++) {
        int key = kf * 16 + prow;
        int byteoff = (key * 128 + ks * 64 + hi * 16) ^ ((key & 7) << 4);
        bf16x8 kfrag = *(const bf16x8*)(KsB + byteoff);
        mfma_bf16(s[kf], kfrag, qf[ks]);
      }
    }
    __builtin_amdgcn_s_setprio(0);

    // tile max via max3 tree (cross-hi reduce: 2 shfl)
    float t0 = fmaxf(fmaxf(s[0][0], s[0][1]), s[0][2]);
    float t1 = fmaxf(fmaxf(s[0][3], s[1][0]), s[1][1]);
    float t2 = fmaxf(fmaxf(s[1][2], s[1][3]), s[2][0]);
    float t3 = fmaxf(fmaxf(s[2][1], s[2][2]), s[2][3]);
    float t4 = fmaxf(fmaxf(s[3][0], s[3][1]), s[3][2]);
    float tm = fmaxf(fmaxf(fmaxf(t0, t1), t2), fmaxf(fmaxf(t3, t4), s[3][3]));
    tm = fmaxf(tm, __shfl_xor(tm, 16));
    tm = fmaxf(tm, __shfl_xor(tm, 32));

    // defer-max: only rescale when the max grew materially (wave-uniform branch)
    if (!__all(tm - m_run <= THR)) {
      float mn = fmaxf(m_run, tm);
      float alpha = __builtin_exp2f(m_run - mn);
      m_run = mn;
      l_part *= alpha;
#pragma unroll
      for (int r = 0; r < 4; r++) {
        float ar = __shfl(alpha, hi * 4 + r);
#pragma unroll
        for (int fd = 0; fd < 4; fd++) o[fd][r] *= ar;
      }
    }

    // p = 2^(s - m), pack pairs to bf16, lane-local partial sum
    float rs0 = 0.0f, rs1 = 0.0f;
#pragma unroll
    for (int kf = 0; kf < 4; kf++) {
      float p0 = __builtin_exp2f(s[kf][0] - m_run);
      float p1 = __builtin_exp2f(s[kf][1] - m_run);
      float p2 = __builtin_exp2f(s[kf][2] - m_run);
      float p3 = __builtin_exp2f(s[kf][3] - m_run);
      rs0 += p0 + p1;
      rs1 += p2 + p3;
      __hip_bfloat162 h01 = __float22bfloat162_rn(make_float2(p0, p1));
      __hip_bfloat162 h23 = __float22bfloat162_rn(make_float2(p2, p3));
      int2 w;
      w.x = *(int*)&h01;
      w.y = *(int*)&h23;
      int wb = (prow * 128 + kf * 32 + hi * 8) ^ ((prow & 7) << 4);
      *(int2*)(PwB + wb) = w;
    }
    l_part += rs0 + rs1;

    // O += P · V
    __builtin_amdgcn_s_setprio(1);
#pragma unroll
    for (int ks = 0; ks < 2; ks++) {
      int pbyte = (prow * 128 + ks * 64 + hi * 16) ^ ((prow & 7) << 4);
      bf16x8 pa = *(const bf16x8*)(PwB + pbyte);
#pragma unroll
      for (int fd = 0; fd < 4; fd++) {
        int d = fd * 16 + prow;
        int vbyte = (d * 128 + ks * 64 + hi * 16) ^ ((d & 7) << 4);
        bf16x8 vf = *(const bf16x8*)(VtB + vbyte);
        mfma_bf16(o[fd], pa, vf);
      }
    }
    __builtin_amdgcn_s_setprio(0);
    __builtin_amdgcn_sched_barrier(0);
    __builtin_amdgcn_s_barrier();
    cur ^= 1;
  }
#undef STAGE

  // epilogue: reduce l across hi-groups, then out[b][t][h*64+d]
  float l_run = l_part;
  l_run += __shfl_xor(l_run, 16);
  l_run += __shfl_xor(l_run, 32);
  const int b = bh >> 4, h = bh & 15;
#pragma unroll
  for (int r = 0; r < 4; r++) {
    float lr = __shfl(l_run, hi * 4 + r);
    float inv = 1.0f / lr;
    int trow = q0 + wave * 16 + hi * 4 + r;
#pragma unroll
    for (int fd = 0; fd < 4; fd++) {
      int col = h * 64 + fd * 16 + prow;
      Ob[((size_t)(b * 2048 + trow)) * 1024 + col] = __float2bfloat16(o[fd][r] * inv);
    }
  }
}

extern "C" void kernel_launch(void* const* d_in, const int* in_sizes, int n_in,
                              void* d_out, int out_size, void* d_ws, size_t ws_size,
                              hipStream_t stream) {
  const float* x = (const float*)d_in[0];
  const float* w_qkv = (const float*)d_in[1];
  const float* w_out = (const float*)d_in[2];
  const float* b_out = (const float*)d_in[3];
  float* out = (float*)d_out;

  size_t need = (size_t)37748736 * 2;
  if (ws_size < need) return;
  __hip_bfloat16* wsp = (__hip_bfloat16*)d_ws;
  __hip_bfloat16* x_bf = wsp;                          // 8192*1024 (reused as attn out)
  __hip_bfloat16* wqkv_t = x_bf + 8192 * 1024;         // 3072*1024
  __hip_bfloat16* wout_t = wqkv_t + 3072 * 1024;       // 1024*1024
  __hip_bfloat16* qb = wout_t + 1024 * 1024;           // [bh][t][64]
  __hip_bfloat16* kb = qb + 8388608;                   // [bh][t][64]
  __hip_bfloat16* vt = kb + 8388608;                   // [bh][d][2048]
  __hip_bfloat16* ab = x_bf;

  cvt_f32_bf16<<<8192, 256, 0, stream>>>(x, x_bf, 8192 * 1024 / 4);
  transpose_cvt<<<dim3(3072 / 32, 1024 / 32), dim3(32, 8), 0, stream>>>(w_qkv, wqkv_t, 1024, 3072);
  transpose_cvt<<<dim3(1024 / 32, 1024 / 32), dim3(32, 8), 0, stream>>>(w_out, wout_t, 1024, 1024);
  gemm_bf16<0><<<dim3(16, 64), 256, 0, stream>>>(x_bf, wqkv_t, 8192, 3072, 1024,
                                                 qb, kb, nullptr, nullptr, nullptr);
  gemm_bf16<2><<<dim3(8, 64), 256, 0, stream>>>(x_bf, wqkv_t, 8192, 3072, 1024,
                                                nullptr, nullptr, vt, nullptr, nullptr);
  attn_fwd<<<2048, 256, 0, stream>>>(qb, kb, vt, ab);
  gemm_bf16<1><<<dim3(8, 64), 256, 0, stream>>>(ab, wout_t, 8192, 1024, 1024,
                                                nullptr, nullptr, nullptr, out, b_out);
}

// Round 5
// 248.480 us; speedup vs baseline: 1.0047x; 1.0047x over previous
//
#include <hip/hip_runtime.h>
#include <hip/hip_bf16.h>
#include <stdint.h>

// B=4, T=2048, INPUT_DIM=1024, DIM=64, H=16
typedef __attribute__((ext_vector_type(8))) short bf16x8;
typedef __attribute__((ext_vector_type(4))) short s16x4;
typedef __attribute__((ext_vector_type(4))) float f32x4;
typedef __attribute__((ext_vector_type(16))) float f32x16;

__device__ __forceinline__ void mfma_bf16(f32x4& c, bf16x8 a, bf16x8 b) {
  asm("v_mfma_f32_16x16x32_bf16 %0, %1, %2, %0" : "+v"(c) : "v"(a), "v"(b));
}
__device__ __forceinline__ void mfma32_bf16(f32x16& c, bf16x8 a, bf16x8 b) {
  asm("v_mfma_f32_32x32x16_bf16 %0, %1, %2, %0" : "+v"(c) : "v"(a), "v"(b));
}

__device__ __forceinline__ void gload_lds16(const void* g, void* lds) {
  __builtin_amdgcn_global_load_lds(
      (const __attribute__((address_space(1))) void*)g,
      (__attribute__((address_space(3))) void*)lds, 16, 0, 0);
}

// ---------------- f32 -> bf16 convert (vectorized) ----------------
__global__ void cvt_f32_bf16(const float* __restrict__ in, __hip_bfloat16* __restrict__ out, int n4) {
  int i = blockIdx.x * blockDim.x + threadIdx.x;
  if (i >= n4) return;
  float4 v = reinterpret_cast<const float4*>(in)[i];
  __hip_bfloat162 a = __float22bfloat162_rn(make_float2(v.x, v.y));
  __hip_bfloat162 b = __float22bfloat162_rn(make_float2(v.z, v.w));
  reinterpret_cast<__hip_bfloat162*>(out)[i * 2]     = a;
  reinterpret_cast<__hip_bfloat162*>(out)[i * 2 + 1] = b;
}

// ------------- transpose [R][C] f32 -> [C][R] bf16 -------------
__global__ void transpose_cvt(const float* __restrict__ in, __hip_bfloat16* __restrict__ out,
                              int R, int C) {
  __shared__ float tile[32][33];
  int c0 = blockIdx.x * 32, r0 = blockIdx.y * 32;
#pragma unroll
  for (int k = 0; k < 4; k++)
    tile[threadIdx.y + 8 * k][threadIdx.x] =
        in[(size_t)(r0 + threadIdx.y + 8 * k) * C + c0 + threadIdx.x];
  __syncthreads();
#pragma unroll
  for (int k = 0; k < 4; k++)
    out[(size_t)(c0 + threadIdx.y + 8 * k) * R + r0 + threadIdx.x] =
        __float2bfloat16(tile[threadIdx.x][threadIdx.y + 8 * k]);
}

// ---------------- bf16 GEMM, m97 structure: 128x128 tile, BK=32 ----------------
// A: [M][K] row-major bf16 ; Bt: [N][K] row-major bf16
// MODE 0: scatter Q (scaled 0.125*log2e) / K into [B,H,T,64]   (n-cols 0..2047)
// MODE 1: f32 out + bias
// MODE 2: V-tiles (n-cols 2048..3071): swapped mfma -> C^T, scatter Vt [bh][d][t]
template <int MODE>
__global__ __launch_bounds__(256) void gemm_bf16(
    const __hip_bfloat16* __restrict__ A, const __hip_bfloat16* __restrict__ Bt,
    int M, int N, int K,
    __hip_bfloat16* __restrict__ qb, __hip_bfloat16* __restrict__ kb,
    __hip_bfloat16* __restrict__ vt,
    float* __restrict__ outp, const float* __restrict__ bias) {
  constexpr int BK = 32;
  __shared__ __align__(16) __hip_bfloat16 As[128 * BK];
  __shared__ __align__(16) __hip_bfloat16 Bs[128 * BK];
  const int tid = threadIdx.x;
  const int wave = tid >> 6, lane = tid & 63;
  const int wr = wave >> 1, wc = wave & 1;
  const int m0 = blockIdx.y * 128;
  const int n0 = (MODE == 2 ? 2048 : 0) + blockIdx.x * 128;

  f32x4 acc[4][4];
#pragma unroll
  for (int i = 0; i < 4; i++)
#pragma unroll
    for (int j = 0; j < 4; j++) acc[i][j] = (f32x4)(0.0f);

  const int c0 = wave * 2, c1 = c0 + 1;
  const int srow0 = c0 * 16 + (lane >> 2);
  const int srow1 = c1 * 16 + (lane >> 2);
  const int scol = (lane & 3) * 8;
  const __hip_bfloat16* Ag0 = A + (size_t)(m0 + srow0) * K + scol;
  const __hip_bfloat16* Ag1 = A + (size_t)(m0 + srow1) * K + scol;
  const __hip_bfloat16* Bg0 = Bt + (size_t)(n0 + srow0) * K + scol;
  const __hip_bfloat16* Bg1 = Bt + (size_t)(n0 + srow1) * K + scol;
  __hip_bfloat16* AsP0 = &As[c0 * 512];
  __hip_bfloat16* AsP1 = &As[c1 * 512];
  __hip_bfloat16* BsP0 = &Bs[c0 * 512];
  __hip_bfloat16* BsP1 = &Bs[c1 * 512];

  for (int kk = 0; kk < K; kk += BK) {
    gload_lds16(Ag0 + kk, AsP0);
    gload_lds16(Ag1 + kk, AsP1);
    gload_lds16(Bg0 + kk, BsP0);
    gload_lds16(Bg1 + kk, BsP1);
    __syncthreads();
    bf16x8 af[4], bfr[4];
#pragma unroll
    for (int i = 0; i < 4; i++)
      af[i] = *(const bf16x8*)&As[(wr * 64 + i * 16 + (lane & 15)) * BK + (lane >> 4) * 8];
#pragma unroll
    for (int j = 0; j < 4; j++)
      bfr[j] = *(const bf16x8*)&Bs[(wc * 64 + j * 16 + (lane & 15)) * BK + (lane >> 4) * 8];
#pragma unroll
    for (int i = 0; i < 4; i++)
#pragma unroll
      for (int j = 0; j < 4; j++) {
        if constexpr (MODE == 2)
          mfma_bf16(acc[i][j], bfr[j], af[i]);  // D = C^T fragment
        else
          mfma_bf16(acc[i][j], af[i], bfr[j]);
      }
    __syncthreads();
  }

  if constexpr (MODE == 0) {
#pragma unroll
    for (int j = 0; j < 4; j++) {
      int col = n0 + wc * 64 + j * 16 + (lane & 15);  // col = sel*1024 + h*64 + d
      int sel = col >> 10;                            // 0=Q, 1=K
      int h = (col >> 6) & 15;
      int d = col & 63;
      __hip_bfloat16* dst = sel ? kb : qb;
      // Q: fold 1/sqrt(64) AND log2(e) so softmax runs in base-2 domain
      float scl = sel ? 1.0f : 0.18033688f;
#pragma unroll
      for (int i = 0; i < 4; i++) {
#pragma unroll
        for (int r = 0; r < 4; r++) {
          int row = m0 + wr * 64 + i * 16 + (lane >> 4) * 4 + r;  // b*2048 + t
          int b = row >> 11, t = row & 2047;
          dst[(((size_t)b * 16 + h) * 2048 + t) * 64 + d] = __float2bfloat16(acc[i][j][r] * scl);
        }
      }
    }
  } else if constexpr (MODE == 2) {
    // acc[i][j]: col(lane&15) = m-index (t), row(reg) = n-index (head/d)
#pragma unroll
    for (int j = 0; j < 4; j++) {
#pragma unroll
      for (int r = 0; r < 4; r++) {
        int nrow = n0 + wc * 64 + j * 16 + (lane >> 4) * 4 + r;  // 2048 + h*64 + d
        int h = (nrow >> 6) & 15;
        int d = nrow & 63;
#pragma unroll
        for (int i = 0; i < 4; i++) {
          int tcol = m0 + wr * 64 + i * 16 + (lane & 15);  // b*2048 + t
          int b = tcol >> 11, t = tcol & 2047;
          vt[(((size_t)b * 16 + h) * 64 + d) * 2048 + t] = __float2bfloat16(acc[i][j][r]);
        }
      }
    }
  } else {
#pragma unroll
    for (int j = 0; j < 4; j++) {
      int col = n0 + wc * 64 + j * 16 + (lane & 15);
      float bv = bias[col];
#pragma unroll
      for (int i = 0; i < 4; i++) {
#pragma unroll
        for (int r = 0; r < 4; r++) {
          int row = m0 + wr * 64 + i * 16 + (lane >> 4) * 4 + r;
          outp[(size_t)row * N + col] = acc[i][j][r] + bv;
        }
      }
    }
  }
}

// ---------------- flash attention, 32x32 MFMA, in-register P ----------------
// Q,K: [bh][t][64] bf16 (Q pre-scaled by 0.125*log2e -> base-2 softmax).
// Vt: [bh][d][2048] bf16. Out: [b*T + t][1024] bf16.
// 4 waves x 32 q-rows = 128 rows/block; KV tiles of 64, double-buffered LDS.
// QK^T: S^T = mfma32(A=K, B=Q): lane holds S[key=(reg&3)+8*(reg>>2)+4*half (+32kb)][qrow=lane&31].
// P redistributed to PV B-frags via cvt_pk + v_permlane32_swap (no LDS).
//   permlane32_swap semantics: vdst[32:63] <-> vsrc[0:31]. To build B-frag word0
//   = (lo: cw0@lo, hi: cw2@lo) and word2 = (lo: cw0@hi, hi: cw2@hi), issue
//   swap(vdst=cw0, vsrc=cw2)  [round-4 bug: operands were reversed].
// PV: O^T = mfma32(A=V^T, B=P): lane holds O^T[d][qrow=lane&31].
__global__ __launch_bounds__(256) void attn_fwd(
    const __hip_bfloat16* __restrict__ Qb, const __hip_bfloat16* __restrict__ Kb,
    const __hip_bfloat16* __restrict__ Vtg, __hip_bfloat16* __restrict__ Ob) {
  constexpr int T = 2048;
  constexpr float THR = 11.5f;  // log2 domain
  __shared__ __align__(16) __hip_bfloat16 Ks[2][4096];  // [key][d] image, swizzled
  __shared__ __align__(16) __hip_bfloat16 Vs[2][4096];  // [d][key] image, swizzled
  const int tid = threadIdx.x, wave = tid >> 6, lane = tid & 63;

  // XCD-aware swizzle: 1024 blocks = 8 XCD x 128; XCD x gets bh 8x..8x+7
  int id = ((int)blockIdx.x & 7) * 128 + ((int)blockIdx.x >> 3);
  const int bh = id >> 4, q0 = (id & 15) * 128;
  const size_t baseQ = (size_t)bh * T * 64;
  const size_t baseV = (size_t)bh * 64 * T;
  const int l31 = lane & 31, half = lane >> 5;

  // Q fragments (B-operand): lane holds Q[qrow=l31][k = 16ks + half*8 + j]
  bf16x8 qf[4];
  const int qrow = q0 + wave * 32 + l31;
#pragma unroll
  for (int ks = 0; ks < 4; ks++)
    qf[ks] = *(const bf16x8*)&Qb[baseQ + (size_t)qrow * 64 + ks * 16 + half * 8];

  float m_run = -3.0e38f;
  float l_part = 0.0f;  // lane-local partial over this lane's 32 keys/tile
  f32x16 o0 = (f32x16)(0.0f), o1 = (f32x16)(0.0f);

  const int sr = lane >> 3;         // 0..7
  const int q8 = (lane & 7) ^ sr;   // pre-swizzled 16B-chunk within row
  const char* KgB = (const char*)(Kb + baseQ);
  const char* VgB = (const char*)(Vtg + baseV);
  const int cc0 = wave * 2, cc1 = cc0 + 1;
  const int swz = (l31 & 7) << 4;   // read-side XOR for rows key/d (row&7 = lane&7)

#define STAGE(kt, buf)                                                                        \
  do {                                                                                        \
    char* kd = (char*)Ks[buf];                                                                \
    char* vd = (char*)Vs[buf];                                                                \
    gload_lds16(KgB + (size_t)((kt) * 64 + cc0 * 8 + sr) * 128 + q8 * 16, kd + cc0 * 1024);   \
    gload_lds16(KgB + (size_t)((kt) * 64 + cc1 * 8 + sr) * 128 + q8 * 16, kd + cc1 * 1024);   \
    gload_lds16(VgB + (size_t)(cc0 * 8 + sr) * 4096 + (kt) * 128 + q8 * 16, vd + cc0 * 1024); \
    gload_lds16(VgB + (size_t)(cc1 * 8 + sr) * 4096 + (kt) * 128 + q8 * 16, vd + cc1 * 1024); \
  } while (0)

  STAGE(0, 0);
  int cur = 0;

  for (int kt = 0; kt < T / 64; kt++) {
    if (kt < T / 64 - 1) {
      STAGE(kt + 1, cur ^ 1);
      asm volatile("s_waitcnt vmcnt(4)" ::: "memory");  // cur tile landed; 4 prefetch in flight
    } else {
      asm volatile("s_waitcnt vmcnt(0)" ::: "memory");
    }
    __builtin_amdgcn_s_barrier();
    __builtin_amdgcn_sched_barrier(0);
    const char* KsB = (const char*)Ks[cur];
    const char* VtB = (const char*)Vs[cur];

    // ---- QK: S^T[key][qrow], key-blocks kb=0,1 ----
    f32x16 s0 = (f32x16)(0.0f), s1 = (f32x16)(0.0f);
    __builtin_amdgcn_s_setprio(1);
#pragma unroll
    for (int ks = 0; ks < 4; ks++) {
      bf16x8 kf0 = *(const bf16x8*)(KsB + ((l31 * 128 + ks * 32 + half * 16) ^ swz));
      bf16x8 kf1 = *(const bf16x8*)(KsB + (((32 + l31) * 128 + ks * 32 + half * 16) ^ swz));
      mfma32_bf16(s0, kf0, qf[ks]);
      mfma32_bf16(s1, kf1, qf[ks]);
    }
    __builtin_amdgcn_s_setprio(0);

    // ---- softmax (qrow = l31 is lane-local; only cross-half shfl needed) ----
    float mx[8];
#pragma unroll
    for (int i = 0; i < 8; i++)
      mx[i] = fmaxf(fmaxf(s0[2 * i], s0[2 * i + 1]), fmaxf(s1[2 * i], s1[2 * i + 1]));
    float tm = fmaxf(fmaxf(fmaxf(mx[0], mx[1]), fmaxf(mx[2], mx[3])),
                     fmaxf(fmaxf(mx[4], mx[5]), fmaxf(mx[6], mx[7])));
    tm = fmaxf(tm, __shfl_xor(tm, 32));

    if (!__all(tm - m_run <= THR)) {
      float mn = fmaxf(m_run, tm);
      float alpha = __builtin_exp2f(m_run - mn);
      m_run = mn;
      l_part *= alpha;
#pragma unroll
      for (int r = 0; r < 16; r++) {
        o0[r] *= alpha;
        o1[r] *= alpha;
      }
    }

    float rs0 = 0.0f, rs1 = 0.0f;
#pragma unroll
    for (int r = 0; r < 16; r++) {
      s0[r] = __builtin_exp2f(s0[r] - m_run);
      s1[r] = __builtin_exp2f(s1[r] - m_run);
      rs0 += s0[r];
      rs1 += s1[r];
    }
    l_part += rs0 + rs1;

    // ---- P -> PV B-fragments in-register; PV: O^T += V^T . P ----
    __builtin_amdgcn_s_setprio(1);
#pragma unroll
    for (int kb = 0; kb < 2; kb++) {
      int cw[8];
#pragma unroll
      for (int m = 0; m < 8; m++) {
        float pa = (kb == 0) ? s0[2 * m] : s1[2 * m];
        float pb = (kb == 0) ? s0[2 * m + 1] : s1[2 * m + 1];
        __hip_bfloat162 h2 = __float22bfloat162_rn(make_float2(pa, pb));
        cw[m] = *(int*)&h2;
      }
      // vdst[32:63] <-> vsrc[0:31]; vdst = low-key word (becomes word0/1),
      // vsrc = high-key word (becomes word2/3)
      asm("v_permlane32_swap_b32 %0, %1" : "+v"(cw[0]), "+v"(cw[2]));
      asm("v_permlane32_swap_b32 %0, %1" : "+v"(cw[1]), "+v"(cw[3]));
      asm("v_permlane32_swap_b32 %0, %1" : "+v"(cw[4]), "+v"(cw[6]));
      asm("v_permlane32_swap_b32 %0, %1" : "+v"(cw[5]), "+v"(cw[7]));
      int4 w0 = make_int4(cw[0], cw[1], cw[2], cw[3]);
      int4 w1 = make_int4(cw[4], cw[5], cw[6], cw[7]);
      bf16x8 pb0 = *(bf16x8*)&w0;   // B-frag, keys kb*32 + 0..15
      bf16x8 pb1 = *(bf16x8*)&w1;   // B-frag, keys kb*32 + 16..31
      // V^T A-frags: A[d][key = kb*32 + (0..15 | 16..31)]
      bf16x8 va0 = *(const bf16x8*)(VtB + ((l31 * 128 + kb * 64 + half * 16) ^ swz));
      bf16x8 vb0 = *(const bf16x8*)(VtB + (((32 + l31) * 128 + kb * 64 + half * 16) ^ swz));
      bf16x8 va1 = *(const bf16x8*)(VtB + ((l31 * 128 + kb * 64 + 32 + half * 16) ^ swz));
      bf16x8 vb1 = *(const bf16x8*)(VtB + (((32 + l31) * 128 + kb * 64 + 32 + half * 16) ^ swz));
      mfma32_bf16(o0, va0, pb0);
      mfma32_bf16(o1, vb0, pb0);
      mfma32_bf16(o0, va1, pb1);
      mfma32_bf16(o1, vb1, pb1);
    }
    __builtin_amdgcn_s_setprio(0);
    __builtin_amdgcn_sched_barrier(0);
    __builtin_amdgcn_s_barrier();
    cur ^= 1;
  }
#undef STAGE

  // ---- epilogue: l reduce across halves (same qrow), normalize, store ----
  float l_run = l_part + __shfl_xor(l_part, 32);
  float inv = 1.0f / l_run;
  const int b = bh >> 4, h = bh & 15;
  const int trow = q0 + wave * 32 + l31;
  __hip_bfloat16* orow = Ob + ((size_t)(b * 2048 + trow)) * 1024 + h * 64;
#pragma unroll
  for (int db = 0; db < 2; db++) {
#pragma unroll
    for (int rq = 0; rq < 4; rq++) {
      int d0 = db * 32 + rq * 8 + half * 4;
      s16x4 w;
#pragma unroll
      for (int e = 0; e < 4; e++) {
        float val = (db == 0 ? o0[rq * 4 + e] : o1[rq * 4 + e]) * inv;
        w[e] = (short)__bfloat16_as_short(__float2bfloat16(val));
      }
      *(s16x4*)(orow + d0) = w;
    }
  }
}

extern "C" void kernel_launch(void* const* d_in, const int* in_sizes, int n_in,
                              void* d_out, int out_size, void* d_ws, size_t ws_size,
                              hipStream_t stream) {
  const float* x = (const float*)d_in[0];
  const float* w_qkv = (const float*)d_in[1];
  const float* w_out = (const float*)d_in[2];
  const float* b_out = (const float*)d_in[3];
  float* out = (float*)d_out;

  size_t need = (size_t)37748736 * 2;
  if (ws_size < need) return;
  __hip_bfloat16* wsp = (__hip_bfloat16*)d_ws;
  __hip_bfloat16* x_bf = wsp;                          // 8192*1024 (reused as attn out)
  __hip_bfloat16* wqkv_t = x_bf + 8192 * 1024;         // 3072*1024
  __hip_bfloat16* wout_t = wqkv_t + 3072 * 1024;       // 1024*1024
  __hip_bfloat16* qb = wout_t + 1024 * 1024;           // [bh][t][64]
  __hip_bfloat16* kb = qb + 8388608;                   // [bh][t][64]
  __hip_bfloat16* vt = kb + 8388608;                   // [bh][d][2048]
  __hip_bfloat16* ab = x_bf;

  cvt_f32_bf16<<<8192, 256, 0, stream>>>(x, x_bf, 8192 * 1024 / 4);
  transpose_cvt<<<dim3(3072 / 32, 1024 / 32), dim3(32, 8), 0, stream>>>(w_qkv, wqkv_t, 1024, 3072);
  transpose_cvt<<<dim3(1024 / 32, 1024 / 32), dim3(32, 8), 0, stream>>>(w_out, wout_t, 1024, 1024);
  gemm_bf16<0><<<dim3(16, 64), 256, 0, stream>>>(x_bf, wqkv_t, 8192, 3072, 1024,
                                                 qb, kb, nullptr, nullptr, nullptr);
  gemm_bf16<2><<<dim3(8, 64), 256, 0, stream>>>(x_bf, wqkv_t, 8192, 3072, 1024,
                                                nullptr, nullptr, vt, nullptr, nullptr);
  attn_fwd<<<1024, 256, 0, stream>>>(qb, kb, vt, ab);
  gemm_bf16<1><<<dim3(8, 64), 256, 0, stream>>>(ab, wout_t, 8192, 1024, 1024,
                                                nullptr, nullptr, nullptr, out, b_out);
}

// Round 6
// 236.258 us; speedup vs baseline: 1.0566x; 1.0517x over previous
//
#include <hip/hip_runtime.h>
#include <hip/hip_bf16.h>
#include <stdint.h>

// B=4, T=2048, INPUT_DIM=1024, DIM=64, H=16
typedef __attribute__((ext_vector_type(8))) short bf16x8;
typedef __attribute__((ext_vector_type(4))) short s16x4;
typedef __attribute__((ext_vector_type(4))) float f32x4;
typedef __attribute__((ext_vector_type(16))) float f32x16;

__device__ __forceinline__ void mfma_bf16(f32x4& c, bf16x8 a, bf16x8 b) {
  asm("v_mfma_f32_16x16x32_bf16 %0, %1, %2, %0" : "+v"(c) : "v"(a), "v"(b));
}
__device__ __forceinline__ void mfma32_bf16(f32x16& c, bf16x8 a, bf16x8 b) {
  asm("v_mfma_f32_32x32x16_bf16 %0, %1, %2, %0" : "+v"(c) : "v"(a), "v"(b));
}

__device__ __forceinline__ void gload_lds16(const void* g, void* lds) {
  __builtin_amdgcn_global_load_lds(
      (const __attribute__((address_space(1))) void*)g,
      (__attribute__((address_space(3))) void*)lds, 16, 0, 0);
}

// ---------------- f32 -> bf16 convert (vectorized) ----------------
__global__ void cvt_f32_bf16(const float* __restrict__ in, __hip_bfloat16* __restrict__ out, int n4) {
  int i = blockIdx.x * blockDim.x + threadIdx.x;
  if (i >= n4) return;
  float4 v = reinterpret_cast<const float4*>(in)[i];
  __hip_bfloat162 a = __float22bfloat162_rn(make_float2(v.x, v.y));
  __hip_bfloat162 b = __float22bfloat162_rn(make_float2(v.z, v.w));
  reinterpret_cast<__hip_bfloat162*>(out)[i * 2]     = a;
  reinterpret_cast<__hip_bfloat162*>(out)[i * 2 + 1] = b;
}

// ------------- transpose [R][C] f32 -> [C][R] bf16 -------------
__global__ void transpose_cvt(const float* __restrict__ in, __hip_bfloat16* __restrict__ out,
                              int R, int C) {
  __shared__ float tile[32][33];
  int c0 = blockIdx.x * 32, r0 = blockIdx.y * 32;
#pragma unroll
  for (int k = 0; k < 4; k++)
    tile[threadIdx.y + 8 * k][threadIdx.x] =
        in[(size_t)(r0 + threadIdx.y + 8 * k) * C + c0 + threadIdx.x];
  __syncthreads();
#pragma unroll
  for (int k = 0; k < 4; k++)
    out[(size_t)(c0 + threadIdx.y + 8 * k) * R + r0 + threadIdx.x] =
        __float2bfloat16(tile[threadIdx.x][threadIdx.y + 8 * k]);
}

// ---------------- bf16 GEMM, m97 structure: 128x128 tile, BK=32 ----------------
// A: [M][K] row-major bf16 ; Bt: [N][K] row-major bf16
// MODE 0: scatter Q (scaled 0.125*log2e) / K into [B,H,T,64]   (n-cols 0..2047)
// MODE 1: f32 out + bias
// MODE 2: V-tiles (n-cols 2048..3071): swapped mfma -> C^T, scatter Vt [bh][d][t]
template <int MODE>
__global__ __launch_bounds__(256) void gemm_bf16(
    const __hip_bfloat16* __restrict__ A, const __hip_bfloat16* __restrict__ Bt,
    int M, int N, int K,
    __hip_bfloat16* __restrict__ qb, __hip_bfloat16* __restrict__ kb,
    __hip_bfloat16* __restrict__ vt,
    float* __restrict__ outp, const float* __restrict__ bias) {
  constexpr int BK = 32;
  __shared__ __align__(16) __hip_bfloat16 As[128 * BK];
  __shared__ __align__(16) __hip_bfloat16 Bs[128 * BK];
  const int tid = threadIdx.x;
  const int wave = tid >> 6, lane = tid & 63;
  const int wr = wave >> 1, wc = wave & 1;
  const int m0 = blockIdx.y * 128;
  const int n0 = (MODE == 2 ? 2048 : 0) + blockIdx.x * 128;

  f32x4 acc[4][4];
#pragma unroll
  for (int i = 0; i < 4; i++)
#pragma unroll
    for (int j = 0; j < 4; j++) acc[i][j] = (f32x4)(0.0f);

  const int c0 = wave * 2, c1 = c0 + 1;
  const int srow0 = c0 * 16 + (lane >> 2);
  const int srow1 = c1 * 16 + (lane >> 2);
  const int scol = (lane & 3) * 8;
  const __hip_bfloat16* Ag0 = A + (size_t)(m0 + srow0) * K + scol;
  const __hip_bfloat16* Ag1 = A + (size_t)(m0 + srow1) * K + scol;
  const __hip_bfloat16* Bg0 = Bt + (size_t)(n0 + srow0) * K + scol;
  const __hip_bfloat16* Bg1 = Bt + (size_t)(n0 + srow1) * K + scol;
  __hip_bfloat16* AsP0 = &As[c0 * 512];
  __hip_bfloat16* AsP1 = &As[c1 * 512];
  __hip_bfloat16* BsP0 = &Bs[c0 * 512];
  __hip_bfloat16* BsP1 = &Bs[c1 * 512];

  for (int kk = 0; kk < K; kk += BK) {
    gload_lds16(Ag0 + kk, AsP0);
    gload_lds16(Ag1 + kk, AsP1);
    gload_lds16(Bg0 + kk, BsP0);
    gload_lds16(Bg1 + kk, BsP1);
    __syncthreads();
    bf16x8 af[4], bfr[4];
#pragma unroll
    for (int i = 0; i < 4; i++)
      af[i] = *(const bf16x8*)&As[(wr * 64 + i * 16 + (lane & 15)) * BK + (lane >> 4) * 8];
#pragma unroll
    for (int j = 0; j < 4; j++)
      bfr[j] = *(const bf16x8*)&Bs[(wc * 64 + j * 16 + (lane & 15)) * BK + (lane >> 4) * 8];
#pragma unroll
    for (int i = 0; i < 4; i++)
#pragma unroll
      for (int j = 0; j < 4; j++) {
        if constexpr (MODE == 2)
          mfma_bf16(acc[i][j], bfr[j], af[i]);  // D = C^T fragment
        else
          mfma_bf16(acc[i][j], af[i], bfr[j]);
      }
    __syncthreads();
  }

  if constexpr (MODE == 0) {
#pragma unroll
    for (int j = 0; j < 4; j++) {
      int col = n0 + wc * 64 + j * 16 + (lane & 15);  // col = sel*1024 + h*64 + d
      int sel = col >> 10;                            // 0=Q, 1=K
      int h = (col >> 6) & 15;
      int d = col & 63;
      __hip_bfloat16* dst = sel ? kb : qb;
      // Q: fold 1/sqrt(64) AND log2(e) so softmax runs in base-2 domain
      float scl = sel ? 1.0f : 0.18033688f;
#pragma unroll
      for (int i = 0; i < 4; i++) {
#pragma unroll
        for (int r = 0; r < 4; r++) {
          int row = m0 + wr * 64 + i * 16 + (lane >> 4) * 4 + r;  // b*2048 + t
          int b = row >> 11, t = row & 2047;
          dst[(((size_t)b * 16 + h) * 2048 + t) * 64 + d] = __float2bfloat16(acc[i][j][r] * scl);
        }
      }
    }
  } else if constexpr (MODE == 2) {
    // acc[i][j]: col(lane&15) = m-index (t), row(reg) = n-index (head/d)
#pragma unroll
    for (int j = 0; j < 4; j++) {
#pragma unroll
      for (int r = 0; r < 4; r++) {
        int nrow = n0 + wc * 64 + j * 16 + (lane >> 4) * 4 + r;  // 2048 + h*64 + d
        int h = (nrow >> 6) & 15;
        int d = nrow & 63;
#pragma unroll
        for (int i = 0; i < 4; i++) {
          int tcol = m0 + wr * 64 + i * 16 + (lane & 15);  // b*2048 + t
          int b = tcol >> 11, t = tcol & 2047;
          vt[(((size_t)b * 16 + h) * 64 + d) * 2048 + t] = __float2bfloat16(acc[i][j][r]);
        }
      }
    }
  } else {
#pragma unroll
    for (int j = 0; j < 4; j++) {
      int col = n0 + wc * 64 + j * 16 + (lane & 15);
      float bv = bias[col];
#pragma unroll
      for (int i = 0; i < 4; i++) {
#pragma unroll
        for (int r = 0; r < 4; r++) {
          int row = m0 + wr * 64 + i * 16 + (lane >> 4) * 4 + r;
          outp[(size_t)row * N + col] = acc[i][j][r] + bv;
        }
      }
    }
  }
}

// ---------------- flash attention, 8 waves, 32x32 MFMA, in-register P ----------------
// Q,K: [bh][t][64] bf16 (Q pre-scaled by 0.125*log2e -> base-2 softmax).
// Vt: [bh][d][2048] bf16. Out: [b*T + t][1024] bf16.
// 8 waves x 32 q-rows = 256 rows/block (occupancy: 2 blocks/CU = 4 waves/SIMD so
// softmax-VALU of one wave overlaps MFMA of another); KV tiles of 64, dbuf LDS.
// QK^T: S^T = mfma32(A=K, B=Q) with C preloaded to -m_run (max folded into MFMA,
// no per-key subtract). lane holds S[key][qrow=lane&31].
// P -> PV B-frags via cvt_pk + v_permlane32_swap (vdst[32:63]<->vsrc[0:31]).
// PV: O^T = mfma32(A=V^T, B=P).
__global__ __launch_bounds__(512, 4) void attn_fwd(
    const __hip_bfloat16* __restrict__ Qb, const __hip_bfloat16* __restrict__ Kb,
    const __hip_bfloat16* __restrict__ Vtg, __hip_bfloat16* __restrict__ Ob) {
  constexpr int T = 2048;
  constexpr float THR = 11.5f;  // log2 domain
  __shared__ __align__(16) __hip_bfloat16 Ks[2][4096];  // [key][d] image, swizzled
  __shared__ __align__(16) __hip_bfloat16 Vs[2][4096];  // [d][key] image, swizzled
  const int tid = threadIdx.x, wave = tid >> 6, lane = tid & 63;

  // XCD-aware swizzle: 512 blocks = 8 XCD x 64; XCD x gets bh 8x..8x+7
  int id = ((int)blockIdx.x & 7) * 64 + ((int)blockIdx.x >> 3);
  const int bh = id >> 3, q0 = (id & 7) * 256;
  const size_t baseQ = (size_t)bh * T * 64;
  const size_t baseV = (size_t)bh * 64 * T;
  const int l31 = lane & 31, half = lane >> 5;

  // Q fragments (B-operand): lane holds Q[qrow=l31][k = 16ks + half*8 + j]
  bf16x8 qf[4];
  const int qrow = q0 + wave * 32 + l31;
#pragma unroll
  for (int ks = 0; ks < 4; ks++)
    qf[ks] = *(const bf16x8*)&Qb[baseQ + (size_t)qrow * 64 + ks * 16 + half * 8];

  float m_run = 0.0f;   // base-2 running max; init 0 is safe (defer-check renormalizes)
  float l_part = 0.0f;  // lane-local partial over this lane's 32 keys/tile
  f32x16 o0 = (f32x16)(0.0f), o1 = (f32x16)(0.0f);

  const int sr = lane >> 3;         // 0..7
  const int q8 = (lane & 7) ^ sr;   // pre-swizzled 16B-chunk within row
  const char* KgB = (const char*)(Kb + baseQ);
  const char* VgB = (const char*)(Vtg + baseV);
  const int swz = (l31 & 7) << 4;   // read-side XOR for rows key/d (row&7 = lane&7)

  // wave w stages K-chunk w (rows 8w..8w+7) and V-chunk w (d-rows 8w..8w+7)
#define STAGE(kt, buf)                                                                          \
  do {                                                                                          \
    char* kd = (char*)Ks[buf];                                                                  \
    char* vd = (char*)Vs[buf];                                                                  \
    gload_lds16(KgB + (size_t)((kt) * 64 + wave * 8 + sr) * 128 + q8 * 16, kd + wave * 1024);   \
    gload_lds16(VgB + (size_t)(wave * 8 + sr) * 4096 + (kt) * 128 + q8 * 16, vd + wave * 1024); \
  } while (0)

  STAGE(0, 0);
  int cur = 0;

  for (int kt = 0; kt < T / 64; kt++) {
    if (kt < T / 64 - 1) {
      STAGE(kt + 1, cur ^ 1);
      asm volatile("s_waitcnt vmcnt(2)" ::: "memory");  // cur tile landed; 2 prefetch in flight
    } else {
      asm volatile("s_waitcnt vmcnt(0)" ::: "memory");
    }
    __builtin_amdgcn_s_barrier();
    __builtin_amdgcn_sched_barrier(0);
    const char* KsB = (const char*)Ks[cur];
    const char* VtB = (const char*)Vs[cur];

    // ---- QK: S^T[key][qrow] with C = -m_run (s is already relative to m_run) ----
    f32x16 s0, s1;
#pragma unroll
    for (int r = 0; r < 16; r++) {
      s0[r] = -m_run;
      s1[r] = -m_run;
    }
    __builtin_amdgcn_s_setprio(1);
#pragma unroll
    for (int ks = 0; ks < 4; ks++) {
      bf16x8 kf0 = *(const bf16x8*)(KsB + ((l31 * 128 + ks * 32 + half * 16) ^ swz));
      bf16x8 kf1 = *(const bf16x8*)(KsB + (((32 + l31) * 128 + ks * 32 + half * 16) ^ swz));
      mfma32_bf16(s0, kf0, qf[ks]);
      mfma32_bf16(s1, kf1, qf[ks]);
    }
    __builtin_amdgcn_s_setprio(0);

    // ---- softmax: s is relative to m_run; tile max (relative) via max tree ----
    float mx[8];
#pragma unroll
    for (int i = 0; i < 8; i++)
      mx[i] = fmaxf(fmaxf(s0[2 * i], s0[2 * i + 1]), fmaxf(s1[2 * i], s1[2 * i + 1]));
    float tm = fmaxf(fmaxf(fmaxf(mx[0], mx[1]), fmaxf(mx[2], mx[3])),
                     fmaxf(fmaxf(mx[4], mx[5]), fmaxf(mx[6], mx[7])));
    tm = fmaxf(tm, __shfl_xor(tm, 32));

    // defer-max: rescale only when relative max grew past THR (rare, wave-uniform)
    if (!__all(tm <= THR)) {
      float d = fmaxf(tm, 0.0f);
      float alpha = __builtin_exp2f(-d);
      m_run += d;
      l_part *= alpha;
#pragma unroll
      for (int r = 0; r < 16; r++) {
        s0[r] -= d;
        s1[r] -= d;
        o0[r] *= alpha;
        o1[r] *= alpha;
      }
    }

    float rs0 = 0.0f, rs1 = 0.0f;
#pragma unroll
    for (int r = 0; r < 16; r++) {
      s0[r] = __builtin_exp2f(s0[r]);
      s1[r] = __builtin_exp2f(s1[r]);
      rs0 += s0[r];
      rs1 += s1[r];
    }
    l_part += rs0 + rs1;

    // ---- P -> PV B-fragments in-register; PV: O^T += V^T . P ----
    __builtin_amdgcn_s_setprio(1);
#pragma unroll
    for (int kb = 0; kb < 2; kb++) {
      int cw[8];
#pragma unroll
      for (int m = 0; m < 8; m++) {
        float pa = (kb == 0) ? s0[2 * m] : s1[2 * m];
        float pb = (kb == 0) ? s0[2 * m + 1] : s1[2 * m + 1];
        __hip_bfloat162 h2 = __float22bfloat162_rn(make_float2(pa, pb));
        cw[m] = *(int*)&h2;
      }
      // vdst[32:63] <-> vsrc[0:31]; vdst = low-key word (word0/1), vsrc = high (word2/3)
      asm("v_permlane32_swap_b32 %0, %1" : "+v"(cw[0]), "+v"(cw[2]));
      asm("v_permlane32_swap_b32 %0, %1" : "+v"(cw[1]), "+v"(cw[3]));
      asm("v_permlane32_swap_b32 %0, %1" : "+v"(cw[4]), "+v"(cw[6]));
      asm("v_permlane32_swap_b32 %0, %1" : "+v"(cw[5]), "+v"(cw[7]));
      int4 w0 = make_int4(cw[0], cw[1], cw[2], cw[3]);
      int4 w1 = make_int4(cw[4], cw[5], cw[6], cw[7]);
      bf16x8 pb0 = *(bf16x8*)&w0;   // B-frag, keys kb*32 + 0..15
      bf16x8 pb1 = *(bf16x8*)&w1;   // B-frag, keys kb*32 + 16..31
      // V^T A-frags: A[d][key = kb*32 + (0..15 | 16..31)]
      bf16x8 va0 = *(const bf16x8*)(VtB + ((l31 * 128 + kb * 64 + half * 16) ^ swz));
      bf16x8 vb0 = *(const bf16x8*)(VtB + (((32 + l31) * 128 + kb * 64 + half * 16) ^ swz));
      bf16x8 va1 = *(const bf16x8*)(VtB + ((l31 * 128 + kb * 64 + 32 + half * 16) ^ swz));
      bf16x8 vb1 = *(const bf16x8*)(VtB + (((32 + l31) * 128 + kb * 64 + 32 + half * 16) ^ swz));
      mfma32_bf16(o0, va0, pb0);
      mfma32_bf16(o1, vb0, pb0);
      mfma32_bf16(o0, va1, pb1);
      mfma32_bf16(o1, vb1, pb1);
    }
    __builtin_amdgcn_s_setprio(0);
    __builtin_amdgcn_sched_barrier(0);
    __builtin_amdgcn_s_barrier();
    cur ^= 1;
  }
#undef STAGE

  // ---- epilogue: l reduce across halves (same qrow), normalize, store ----
  float l_run = l_part + __shfl_xor(l_part, 32);
  float inv = 1.0f / l_run;
  const int b = bh >> 4, h = bh & 15;
  const int trow = q0 + wave * 32 + l31;
  __hip_bfloat16* orow = Ob + ((size_t)(b * 2048 + trow)) * 1024 + h * 64;
#pragma unroll
  for (int db = 0; db < 2; db++) {
#pragma unroll
    for (int rq = 0; rq < 4; rq++) {
      int d0 = db * 32 + rq * 8 + half * 4;
      s16x4 w;
#pragma unroll
      for (int e = 0; e < 4; e++) {
        float val = (db == 0 ? o0[rq * 4 + e] : o1[rq * 4 + e]) * inv;
        w[e] = (short)__bfloat16_as_short(__float2bfloat16(val));
      }
      *(s16x4*)(orow + d0) = w;
    }
  }
}

extern "C" void kernel_launch(void* const* d_in, const int* in_sizes, int n_in,
                              void* d_out, int out_size, void* d_ws, size_t ws_size,
                              hipStream_t stream) {
  const float* x = (const float*)d_in[0];
  const float* w_qkv = (const float*)d_in[1];
  const float* w_out = (const float*)d_in[2];
  const float* b_out = (const float*)d_in[3];
  float* out = (float*)d_out;

  size_t need = (size_t)37748736 * 2;
  if (ws_size < need) return;
  __hip_bfloat16* wsp = (__hip_bfloat16*)d_ws;
  __hip_bfloat16* x_bf = wsp;                          // 8192*1024 (reused as attn out)
  __hip_bfloat16* wqkv_t = x_bf + 8192 * 1024;         // 3072*1024
  __hip_bfloat16* wout_t = wqkv_t + 3072 * 1024;       // 1024*1024
  __hip_bfloat16* qb = wout_t + 1024 * 1024;           // [bh][t][64]
  __hip_bfloat16* kb = qb + 8388608;                   // [bh][t][64]
  __hip_bfloat16* vt = kb + 8388608;                   // [bh][d][2048]
  __hip_bfloat16* ab = x_bf;

  cvt_f32_bf16<<<8192, 256, 0, stream>>>(x, x_bf, 8192 * 1024 / 4);
  transpose_cvt<<<dim3(3072 / 32, 1024 / 32), dim3(32, 8), 0, stream>>>(w_qkv, wqkv_t, 1024, 3072);
  transpose_cvt<<<dim3(1024 / 32, 1024 / 32), dim3(32, 8), 0, stream>>>(w_out, wout_t, 1024, 1024);
  gemm_bf16<0><<<dim3(16, 64), 256, 0, stream>>>(x_bf, wqkv_t, 8192, 3072, 1024,
                                                 qb, kb, nullptr, nullptr, nullptr);
  gemm_bf16<2><<<dim3(8, 64), 256, 0, stream>>>(x_bf, wqkv_t, 8192, 3072, 1024,
                                                nullptr, nullptr, vt, nullptr, nullptr);
  attn_fwd<<<512, 512, 0, stream>>>(qb, kb, vt, ab);
  gemm_bf16<1><<<dim3(8, 64), 256, 0, stream>>>(ab, wout_t, 8192, 1024, 1024,
                                                nullptr, nullptr, nullptr, out, b_out);
}